// Round 6
// baseline (202.464 us; speedup 1.0000x reference)
//
#include <hip/hip_runtime.h>
#include <math.h>

// Problem constants (fixed by the reference setup_inputs).
#define N 8192
#define D 64
#define C 100
#define T 30
#define GSTRIDE 32   // padded leading dim of per-class Gram rows
#define ZROWS 32     // z0 rows padded 30 -> 32 for MFMA u-tiles
#define CROWS 112    // W^T rows padded 100 -> 112 (7 MFMA c-tiles)
#define WSTRIDE 20   // per-wave transpose row stride (16 u's + 4 pad)
#define SB 16        // epilogue samples per block

static constexpr float D_LOG_2PI      = 117.62413225019811f; // D * log(2*pi)
static constexpr float EV_BUDGET_F    = 80.992775903017304f; // 0.5 * D * log(4*pi)
static constexpr float LOG_EV_CLAMP_F = 10.0f;

typedef __attribute__((ext_vector_type(8))) short short8x;   // 8 x bf16 bits
typedef __attribute__((ext_vector_type(4))) float floatx4;   // MFMA C/D frag

static __device__ __forceinline__ unsigned short f2bf(float f) {
    __bf16 h = (__bf16)f;                       // RNE convert
    return __builtin_bit_cast(unsigned short, h);
}

// ---------------------------------------------------------------------------
// Kernel X: x -> bf16 (once) and q0[n] = ||x_n||^2.
// ---------------------------------------------------------------------------
__global__ __launch_bounds__(256) void xprep_kernel(
        const float* __restrict__ x,
        unsigned short* __restrict__ xbf,
        float* __restrict__ q0) {
    const int r = blockIdx.x * 32 + (threadIdx.x >> 3);  // sample row
    const int e = threadIdx.x & 7;                       // 8-float chunk
    const float4* xp = (const float4*)(x + (size_t)r * D + e * 8);
    const float4 a = xp[0], b = xp[1];
    short8x o;
    o[0] = f2bf(a.x); o[1] = f2bf(a.y); o[2] = f2bf(a.z); o[3] = f2bf(a.w);
    o[4] = f2bf(b.x); o[5] = f2bf(b.y); o[6] = f2bf(b.z); o[7] = f2bf(b.w);
    *(short8x*)(xbf + (size_t)r * D + e * 8) = o;
    float q = a.x*a.x + a.y*a.y + a.z*a.z + a.w*a.w
            + b.x*b.x + b.y*b.y + b.z*b.z + b.w*b.w;
    q += __shfl_xor(q, 4, 8);
    q += __shfl_xor(q, 2, 8);
    q += __shfl_xor(q, 1, 8);
    if (e == 0) q0[r] = q;
}

// ---------------------------------------------------------------------------
// Kernel Wp: pack W^T (bf16, padded to 112 rows): wtbf[c][d] = W[d][c].
// ---------------------------------------------------------------------------
__global__ __launch_bounds__(256) void wprep_kernel(
        const float* __restrict__ W,
        unsigned short* __restrict__ wtbf) {
    const int i = blockIdx.x * 256 + threadIdx.x;   // grid covers CROWS*D
    const int c = i >> 6, d = i & 63;
    wtbf[i] = f2bf(c < C ? W[d * C + c] : 0.0f);
}

// ---------------------------------------------------------------------------
// Kernel P: per-class precompute (Gram, softplus params, bf16 z0).
// ---------------------------------------------------------------------------
__global__ void prep_kernel(const float* __restrict__ z0,
                            const float* __restrict__ ap,
                            const float* __restrict__ bp,
                            float* __restrict__ Gp,
                            float* __restrict__ alphas,
                            float* __restrict__ betas,
                            unsigned short* __restrict__ z0bf) {
    const int c = blockIdx.x;
    __shared__ float z0s[T * D];
    for (int i = threadIdx.x; i < T * D; i += blockDim.x)
        z0s[i] = z0[c * T * D + i];
    __syncthreads();

    for (int idx = threadIdx.x; idx < T * T; idx += blockDim.x) {
        const int u = idx / T, v = idx % T;
        float s = 0.0f;
        #pragma unroll
        for (int d = 0; d < D; ++d)
            s = fmaf(z0s[u * D + d], z0s[v * D + d], s);
        Gp[(size_t)c * T * GSTRIDE + u * GSTRIDE + v] = s;
    }

    for (int i = threadIdx.x; i < ZROWS * D; i += blockDim.x) {
        const int u = i >> 6;
        z0bf[(size_t)c * ZROWS * D + i] = f2bf(u < T ? z0s[u * D + (i & 63)] : 0.0f);
    }

    if (threadIdx.x < T) {
        const float a = ap[c * T + threadIdx.x];
        const float b = bp[c * T + threadIdx.x];
        const float spa = fmaxf(a, 0.0f) + log1pf(expf(-fabsf(a)));
        const float spb = fmaxf(b, 0.0f) + log1pf(expf(-fabsf(b)));
        alphas[c * T + threadIdx.x] = spa;
        betas[c * T + threadIdx.x]  = -spa + spb;
    }
}

// ---------------------------------------------------------------------------
// Kernel A: flow. Phase 1 = MFMA, mu-SPLIT: the two 16-u halves are computed
// sequentially (acc[4]=16 regs + A[2]=8 live per half, vs 32+16 in R5) —
// R5's all-at-once version + scheduler-hoisted ds_reads spilled 72 dwords/
// thread to scratch (WRITE_SIZE 230 MB, L2 thrashed, 2x slower). xbf is
// re-read per half: +100 MB of L2-resident requests, ~3 us, HBM-invisible.
// Phase 2 = Gram-trick recurrence, G/alpha/beta broadcast from LDS.
// __launch_bounds__(256,4): budget 128 regs; do NOT raise (R4: spill at 6).
// ---------------------------------------------------------------------------
__global__ __launch_bounds__(256, 4) void flow_kernel(
        const unsigned short* __restrict__ xbf,
        const float* __restrict__ q0g,
        const unsigned short* __restrict__ z0bf,
        const float* __restrict__ Gp,
        const float* __restrict__ alphas,
        const float* __restrict__ betas,
        float* __restrict__ lp) {
    const int c    = blockIdx.y;
    const int wv   = threadIdx.x >> 6;
    const int ln   = threadIdx.x & 63;
    const int col  = ln & 15;
    const int quad = ln >> 4;
    const int nb   = blockIdx.x * 256 + wv * 64;
    const int n    = nb + ln;

    __shared__ float Gs[T * GSTRIDE];        // 3840 B
    __shared__ float ab[64];                 // alpha[0..29] | beta at +32
    __shared__ float wlds[4][64 * WSTRIDE];  // 20480 B

    for (int i = threadIdx.x; i < T * GSTRIDE; i += 256)
        Gs[i] = Gp[(size_t)c * T * GSTRIDE + i];
    if (threadIdx.x < T) ab[threadIdx.x] = alphas[c * T + threadIdx.x];
    else if (threadIdx.x >= 32 && threadIdx.x < 32 + T)
        ab[threadIdx.x] = betas[c * T + (threadIdx.x - 32)];
    __syncthreads();

    const unsigned short* zb = z0bf + (size_t)c * ZROWS * D;
    float w[ZROWS];

    #pragma unroll
    for (int mu = 0; mu < 2; ++mu) {
        // A frags for this u-half only (8 regs)
        const short8x A0 = *(const short8x*)(zb + (mu * 16 + col) * D + quad * 8);
        const short8x A1 = *(const short8x*)(zb + (mu * 16 + col) * D + 32 + quad * 8);
        floatx4 acc[4];
        #pragma unroll
        for (int nt = 0; nt < 4; ++nt) acc[nt] = (floatx4)(0.0f);
        #pragma unroll
        for (int nt = 0; nt < 4; ++nt) {
            const unsigned short* bp_ = xbf + (size_t)(nb + nt * 16 + col) * D + quad * 8;
            const short8x B0 = *(const short8x*)(bp_);
            acc[nt] = __builtin_amdgcn_mfma_f32_16x16x32_bf16(A0, B0, acc[nt], 0, 0, 0);
            const short8x B1 = *(const short8x*)(bp_ + 32);
            acc[nt] = __builtin_amdgcn_mfma_f32_16x16x32_bf16(A1, B1, acc[nt], 0, 0, 0);
        }
        // per-wave transpose through LDS (same-wave lockstep, no barrier)
        #pragma unroll
        for (int nt = 0; nt < 4; ++nt)
            *(floatx4*)&wlds[wv][(nt * 16 + col) * WSTRIDE + quad * 4] = acc[nt];
        #pragma unroll
        for (int j = 0; j < 4; ++j) {
            const float4 t = *(const float4*)&wlds[wv][ln * WSTRIDE + j * 4];
            w[mu * 16 + 4 * j + 0] = t.x; w[mu * 16 + 4 * j + 1] = t.y;
            w[mu * 16 + 4 * j + 2] = t.z; w[mu * 16 + 4 * j + 3] = t.w;
        }
    }

    // ---- Phase 2 (verified): true w_t[u] = P*w[u]; q = ||z_t||^2 ----
    float q    = q0g[n];
    float P    = 1.0f;
    float prod = 1.0f;
    float ld   = 0.0f;
    #pragma unroll
    for (int t = 0; t < T; ++t) {
        const float Gtt   = Gs[t * GSTRIDE + t];   // broadcast ds_read
        const float alpha = ab[t];
        const float beta  = ab[32 + t];
        const float wt    = P * w[t];
        float r2 = fmaf(-2.0f, wt, q) + Gtt;
        r2 = fmaxf(r2, 0.0f);
        const float r  = __builtin_amdgcn_sqrtf(r2);
        const float h  = __builtin_amdgcn_rcpf(alpha + r);
        const float bh = beta * h;
        const float f  = 1.0f + bh;
        // det factor: f^63 * (1 + bh*alpha*h);  (1 - h*r == alpha*h)
        const float f2 = f * f, f4 = f2 * f2, f8 = f4 * f4;
        const float f16 = f8 * f8, f32v = f16 * f16;
        float p = f32v * f16; p *= f8; p *= f4; p *= f2; p *= f;  // f^63
        p *= fmaf(bh * alpha, h, 1.0f);
        prod *= p;
        if ((t % 6) == 5) { ld += __logf(prod); prod = 1.0f; }
        // q_{t+1} = f^2 q - 2 f bh wt + bh^2 Gtt
        const float m = bh * f;
        float qn = f2 * q;
        qn = fmaf(m, -2.0f * wt, qn);
        qn = fmaf(bh * bh, Gtt, qn);
        q = qn;
        // scaled-w update over aligned 4-blocks; u <= t updates are harmless
        const float Pn = P * f;
        const float k  = bh * __builtin_amdgcn_rcpf(Pn);
        #pragma unroll
        for (int m4 = 0; m4 < 8; ++m4) {
            if (m4 < (t >> 2)) continue;          // blocks fully in the past
            const float4 g = *(const float4*)&Gs[t * GSTRIDE + 4 * m4];  // broadcast b128
            w[4 * m4 + 0] = fmaf(-k, g.x, w[4 * m4 + 0]);
            w[4 * m4 + 1] = fmaf(-k, g.y, w[4 * m4 + 1]);
            w[4 * m4 + 2] = fmaf(-k, g.z, w[4 * m4 + 2]);
            w[4 * m4 + 3] = fmaf(-k, g.w, w[4 * m4 + 3]);
        }
        P = Pn;
    }
    ld += __logf(prod);

    lp[(size_t)c * N + n] = -0.5f * (D_LOG_2PI + q) + ld;
}

// ---------------------------------------------------------------------------
// Kernel L: logits via MFMA. lgT[c][n] = x[n].W[:,c] + b[c].
// One wave per 16 samples; 7 c-tiles of 16; acc = 1 frag at a time.
// Replaces the R5 epilogue's 448 LDS-sourced FMAs/thread (~65 us LDS-bound).
// ---------------------------------------------------------------------------
__global__ __launch_bounds__(256) void logits_kernel(
        const unsigned short* __restrict__ xbf,
        const unsigned short* __restrict__ wtbf,
        const float* __restrict__ b,
        float* __restrict__ lgT) {
    const int wv   = threadIdx.x >> 6;
    const int ln   = threadIdx.x & 63;
    const int col  = ln & 15;
    const int quad = ln >> 4;
    const int n0   = (blockIdx.x * 4 + wv) * 16;

    const unsigned short* bp_ = xbf + (size_t)(n0 + col) * D + quad * 8;
    const short8x B0 = *(const short8x*)(bp_);
    const short8x B1 = *(const short8x*)(bp_ + 32);

    #pragma unroll
    for (int ct = 0; ct < 7; ++ct) {
        const unsigned short* apq = wtbf + (size_t)(ct * 16 + col) * D + quad * 8;
        const short8x A0 = *(const short8x*)(apq);
        const short8x A1 = *(const short8x*)(apq + 32);
        floatx4 acc = (floatx4)(0.0f);
        acc = __builtin_amdgcn_mfma_f32_16x16x32_bf16(A0, B0, acc, 0, 0, 0);
        acc = __builtin_amdgcn_mfma_f32_16x16x32_bf16(A1, B1, acc, 0, 0, 0);
        #pragma unroll
        for (int j = 0; j < 4; ++j) {
            const int cc = ct * 16 + quad * 4 + j;   // C/D: row=quad*4+j, col=n
            if (cc < C)
                lgT[(size_t)cc * N + n0 + col] = acc[j] + b[cc];
        }
    }
}

// ---------------------------------------------------------------------------
// Kernel C: epilogue, pure reduction now. 512 blocks x 256 thr; 16 samples/
// block, 16 lanes/sample; lp & logit tiles staged coalesced into LDS.
// ---------------------------------------------------------------------------
__global__ __launch_bounds__(256) void epilogue_kernel(
        const float* __restrict__ lp,
        const float* __restrict__ lgT,
        const int* __restrict__ labels,
        const float* __restrict__ freq,
        float* __restrict__ out) {
    const int n0  = blockIdx.x * SB;
    const int tid = threadIdx.x;

    __shared__ float lps[SB][101];   // pad 101
    __shared__ float lgs[SB][101];
    __shared__ float lf[C];
    __shared__ int   lbl[SB];

    for (int i = tid; i < C * SB; i += 256) {          // coalesced 16-runs
        const int cc = i >> 4, s = i & (SB - 1);
        lps[s][cc] = lp[(size_t)cc * N + n0 + s];
        lgs[s][cc] = lgT[(size_t)cc * N + n0 + s];
    }
    if (tid < C) lf[tid] = __logf(freq[tid]);
    if (tid < SB) lbl[tid] = labels[n0 + tid];
    __syncthreads();

    const int s = tid >> 4;          // sample in tile (16-groups in-wave)
    const int k = tid & 15;          // lane within sample group
    const int n = n0 + s;

    float lgt[7];
    float lm = -INFINITY;
    float vm = -INFINITY, vs = 0.0f;   // online logsumexp partial (lp+lf)
    #pragma unroll
    for (int j = 0; j < 7; ++j) {
        const int cc = k + 16 * j;
        if (cc < C) {
            const float v = lps[s][cc] + lf[cc];
            const float m2 = fmaxf(vm, v);
            vs = vs * __expf(vm - m2) + __expf(v - m2);
            vm = m2;
            lgt[j] = lgs[s][cc];
            lm = fmaxf(lm, lgt[j]);
        } else lgt[j] = -INFINITY;
    }

    #pragma unroll
    for (int off = 8; off >= 1; off >>= 1) {
        const float om = __shfl_xor(vm, off, 16);
        const float os = __shfl_xor(vs, off, 16);
        const float m2 = fmaxf(vm, om);
        vs = vs * __expf(vm - m2) + os * __expf(om - m2);
        vm = m2;
        lm = fmaxf(lm, __shfl_xor(lm, off, 16));
    }
    const float marg = vm + __logf(vs);
    const float ev = __expf(fminf(marg + EV_BUDGET_F, LOG_EV_CLAMP_F));

    float ls = 0.0f;
    #pragma unroll
    for (int j = 0; j < 7; ++j)
        if (k + 16 * j < C) ls += __expf(lgt[j] - lm);
    #pragma unroll
    for (int off = 8; off >= 1; off >>= 1)
        ls += __shfl_xor(ls, off, 16);

    const float inv = ev / ls;
    float* __restrict__ outr = out + (size_t)n * (C + 1);
    #pragma unroll
    for (int j = 0; j < 7; ++j) {
        const int cc = k + 16 * j;
        if (cc < C) outr[cc] = log1pf(__expf(lgt[j] - lm) * inv);
    }
    if (k == 0) outr[C] = lps[s][lbl[s]];
}

// ---------------------------------------------------------------------------
extern "C" void kernel_launch(void* const* d_in, const int* in_sizes, int n_in,
                              void* d_out, int out_size, void* d_ws, size_t ws_size,
                              hipStream_t stream) {
    const float* x      = (const float*)d_in[0];
    const int*   labels = (const int*)  d_in[1];
    const float* freq   = (const float*)d_in[2];
    const float* z0     = (const float*)d_in[3];
    const float* ap     = (const float*)d_in[4];
    const float* bp     = (const float*)d_in[5];
    const float* W      = (const float*)d_in[6];
    const float* b      = (const float*)d_in[7];
    float* out = (float*)d_out;

    // Workspace (floats): lp[C*N] | lgT[C*N] | Gp | alpha | beta | z0bf | xbf | wtbf | q0
    float* ws     = (float*)d_ws;
    float* lp     = ws;
    float* lgT    = lp + (size_t)C * N;
    float* Gp     = lgT + (size_t)C * N;
    float* alphas = Gp + (size_t)C * T * GSTRIDE;
    float* betas  = alphas + (size_t)C * T;
    unsigned short* z0bf = (unsigned short*)(betas + (size_t)C * T);
    unsigned short* xbf  = z0bf + (size_t)C * ZROWS * D;
    unsigned short* wtbf = xbf + (size_t)N * D;
    float* q0     = (float*)(wtbf + (size_t)CROWS * D);

    xprep_kernel<<<N / 32, 256, 0, stream>>>(x, xbf, q0);
    wprep_kernel<<<(CROWS * D) / 256, 256, 0, stream>>>(W, wtbf);
    prep_kernel<<<C, 256, 0, stream>>>(z0, ap, bp, Gp, alphas, betas, z0bf);
    flow_kernel<<<dim3(N / 256, C), 256, 0, stream>>>(xbf, q0, z0bf, Gp, alphas, betas, lp);
    logits_kernel<<<N / 64, 256, 0, stream>>>(xbf, wtbf, b, lgT);
    epilogue_kernel<<<N / SB, 256, 0, stream>>>(lp, lgT, labels, freq, out);
}

// Round 7
// 153.696 us; speedup vs baseline: 1.3173x; 1.3173x over previous
//
#include <hip/hip_runtime.h>
#include <math.h>

// Problem constants (fixed by the reference setup_inputs).
#define N 8192
#define D 64
#define C 100
#define T 30
#define GSTRIDE 32   // padded leading dim of per-class Gram rows
#define ZROWS 32     // z0 rows padded 30 -> 32 for MFMA u-tiles
#define CROWS 112    // W^T rows padded 100 -> 112 (7 MFMA c-tiles)
#define WSTRIDE 20   // per-wave transpose row stride (16 u's + 4 pad)
#define SB 16        // epilogue samples per block

static constexpr float D_LOG_2PI      = 117.62413225019811f; // D * log(2*pi)
static constexpr float EV_BUDGET_F    = 80.992775903017304f; // 0.5 * D * log(4*pi)
static constexpr float LOG_EV_CLAMP_F = 10.0f;

typedef __attribute__((ext_vector_type(8))) short short8x;   // 8 x bf16 bits
typedef __attribute__((ext_vector_type(4))) float floatx4;   // MFMA C/D frag

static __device__ __forceinline__ unsigned short f2bf(float f) {
    __bf16 h = (__bf16)f;                       // RNE convert
    return __builtin_bit_cast(unsigned short, h);
}

// ---------------------------------------------------------------------------
// Kernel MP: merged prep (one launch instead of three).
//   blocks [0,256):   xprep  — x -> bf16, q0[n] = ||x_n||^2
//   blocks [256,356): class prep — Gram, softplus params, bf16 z0
//   blocks [356,384): wprep  — pack W^T bf16 padded to 112 rows
// Role is block-uniform -> no divergence inside a block.
// ---------------------------------------------------------------------------
__global__ __launch_bounds__(256) void megaprep_kernel(
        const float* __restrict__ x,
        const float* __restrict__ z0,
        const float* __restrict__ ap,
        const float* __restrict__ bp,
        const float* __restrict__ W,
        unsigned short* __restrict__ xbf,
        float* __restrict__ q0,
        float* __restrict__ Gp,
        float* __restrict__ alphas,
        float* __restrict__ betas,
        unsigned short* __restrict__ z0bf,
        unsigned short* __restrict__ wtbf) {
    const int blk = blockIdx.x;

    if (blk < 256) {                         // ---- xprep ----
        const int r = blk * 32 + (threadIdx.x >> 3);
        const int e = threadIdx.x & 7;
        const float4* xp = (const float4*)(x + (size_t)r * D + e * 8);
        const float4 a = xp[0], b = xp[1];
        short8x o;
        o[0] = f2bf(a.x); o[1] = f2bf(a.y); o[2] = f2bf(a.z); o[3] = f2bf(a.w);
        o[4] = f2bf(b.x); o[5] = f2bf(b.y); o[6] = f2bf(b.z); o[7] = f2bf(b.w);
        *(short8x*)(xbf + (size_t)r * D + e * 8) = o;
        float q = a.x*a.x + a.y*a.y + a.z*a.z + a.w*a.w
                + b.x*b.x + b.y*b.y + b.z*b.z + b.w*b.w;
        q += __shfl_xor(q, 4, 8);
        q += __shfl_xor(q, 2, 8);
        q += __shfl_xor(q, 1, 8);
        if (e == 0) q0[r] = q;
        return;
    }

    if (blk >= 356) {                        // ---- wprep ----
        const int i = (blk - 356) * 256 + threadIdx.x;   // covers CROWS*D
        const int c = i >> 6, d = i & 63;
        wtbf[i] = f2bf(c < C ? W[d * C + c] : 0.0f);
        return;
    }

    // ---- class prep ----
    const int c = blk - 256;
    __shared__ float z0s[T * D];
    for (int i = threadIdx.x; i < T * D; i += blockDim.x)
        z0s[i] = z0[c * T * D + i];
    __syncthreads();

    for (int idx = threadIdx.x; idx < T * T; idx += blockDim.x) {
        const int u = idx / T, v = idx % T;
        float s = 0.0f;
        #pragma unroll
        for (int d = 0; d < D; ++d)
            s = fmaf(z0s[u * D + d], z0s[v * D + d], s);
        Gp[(size_t)c * T * GSTRIDE + u * GSTRIDE + v] = s;
    }

    for (int i = threadIdx.x; i < ZROWS * D; i += blockDim.x) {
        const int u = i >> 6;
        z0bf[(size_t)c * ZROWS * D + i] = f2bf(u < T ? z0s[u * D + (i & 63)] : 0.0f);
    }

    if (threadIdx.x < T) {
        const float a = ap[c * T + threadIdx.x];
        const float b = bp[c * T + threadIdx.x];
        const float spa = fmaxf(a, 0.0f) + log1pf(expf(-fabsf(a)));
        const float spb = fmaxf(b, 0.0f) + log1pf(expf(-fabsf(b)));
        alphas[c * T + threadIdx.x] = spa;
        betas[c * T + threadIdx.x]  = -spa + spb;
    }
}

// ---------------------------------------------------------------------------
// Kernel A: flow. Phase 1 = MFMA (mu-split); Phase 2 = Gram-trick recurrence,
// G/alpha/beta broadcast from LDS.
// REGISTER-BUDGET HISTORY (do not regress):
//   (256,6) R4: budget 85  -> 521 MB scratch spill, catastrophic.
//   (256,4) R5/R6: budget 128 -> still 72 dwords/thread spilled (WRITE 230 MB)
//     — scheduler hoists ~2 iters of Gs ds_reads on top of w[30] live set.
//   (256,3) now: budget ~170 covers the ~136-reg appetite -> no spill,
//     occupancy unchanged (3 waves/EU = 12 waves/CU ~= measured 11.2).
// ---------------------------------------------------------------------------
__global__ __launch_bounds__(256, 3) void flow_kernel(
        const unsigned short* __restrict__ xbf,
        const float* __restrict__ q0g,
        const unsigned short* __restrict__ z0bf,
        const float* __restrict__ Gp,
        const float* __restrict__ alphas,
        const float* __restrict__ betas,
        float* __restrict__ lp) {
    const int c    = blockIdx.y;
    const int wv   = threadIdx.x >> 6;
    const int ln   = threadIdx.x & 63;
    const int col  = ln & 15;
    const int quad = ln >> 4;
    const int nb   = blockIdx.x * 256 + wv * 64;
    const int n    = nb + ln;

    __shared__ float Gs[T * GSTRIDE];        // 3840 B
    __shared__ float ab[64];                 // alpha[0..29] | beta at +32
    __shared__ float wlds[4][64 * WSTRIDE];  // 20480 B

    for (int i = threadIdx.x; i < T * GSTRIDE; i += 256)
        Gs[i] = Gp[(size_t)c * T * GSTRIDE + i];
    if (threadIdx.x < T) ab[threadIdx.x] = alphas[c * T + threadIdx.x];
    else if (threadIdx.x >= 32 && threadIdx.x < 32 + T)
        ab[threadIdx.x] = betas[c * T + (threadIdx.x - 32)];
    __syncthreads();

    const unsigned short* zb = z0bf + (size_t)c * ZROWS * D;
    float w[ZROWS];

    #pragma unroll
    for (int mu = 0; mu < 2; ++mu) {
        const short8x A0 = *(const short8x*)(zb + (mu * 16 + col) * D + quad * 8);
        const short8x A1 = *(const short8x*)(zb + (mu * 16 + col) * D + 32 + quad * 8);
        floatx4 acc[4];
        #pragma unroll
        for (int nt = 0; nt < 4; ++nt) acc[nt] = (floatx4)(0.0f);
        #pragma unroll
        for (int nt = 0; nt < 4; ++nt) {
            const unsigned short* bp_ = xbf + (size_t)(nb + nt * 16 + col) * D + quad * 8;
            const short8x B0 = *(const short8x*)(bp_);
            acc[nt] = __builtin_amdgcn_mfma_f32_16x16x32_bf16(A0, B0, acc[nt], 0, 0, 0);
            const short8x B1 = *(const short8x*)(bp_ + 32);
            acc[nt] = __builtin_amdgcn_mfma_f32_16x16x32_bf16(A1, B1, acc[nt], 0, 0, 0);
        }
        // per-wave transpose through LDS (same-wave lockstep, no barrier)
        #pragma unroll
        for (int nt = 0; nt < 4; ++nt)
            *(floatx4*)&wlds[wv][(nt * 16 + col) * WSTRIDE + quad * 4] = acc[nt];
        #pragma unroll
        for (int j = 0; j < 4; ++j) {
            const float4 t = *(const float4*)&wlds[wv][ln * WSTRIDE + j * 4];
            w[mu * 16 + 4 * j + 0] = t.x; w[mu * 16 + 4 * j + 1] = t.y;
            w[mu * 16 + 4 * j + 2] = t.z; w[mu * 16 + 4 * j + 3] = t.w;
        }
    }

    // ---- Phase 2 (verified): true w_t[u] = P*w[u]; q = ||z_t||^2 ----
    float q    = q0g[n];
    float P    = 1.0f;
    float prod = 1.0f;
    float ld   = 0.0f;
    #pragma unroll
    for (int t = 0; t < T; ++t) {
        const float Gtt   = Gs[t * GSTRIDE + t];   // broadcast ds_read
        const float alpha = ab[t];
        const float beta  = ab[32 + t];
        const float wt    = P * w[t];
        float r2 = fmaf(-2.0f, wt, q) + Gtt;
        r2 = fmaxf(r2, 0.0f);
        const float r  = __builtin_amdgcn_sqrtf(r2);
        const float h  = __builtin_amdgcn_rcpf(alpha + r);
        const float bh = beta * h;
        const float f  = 1.0f + bh;
        // det factor: f^63 * (1 + bh*alpha*h);  (1 - h*r == alpha*h)
        const float f2 = f * f, f4 = f2 * f2, f8 = f4 * f4;
        const float f16 = f8 * f8, f32v = f16 * f16;
        float p = f32v * f16; p *= f8; p *= f4; p *= f2; p *= f;  // f^63
        p *= fmaf(bh * alpha, h, 1.0f);
        prod *= p;
        if ((t % 6) == 5) { ld += __logf(prod); prod = 1.0f; }
        // q_{t+1} = f^2 q - 2 f bh wt + bh^2 Gtt
        const float m = bh * f;
        float qn = f2 * q;
        qn = fmaf(m, -2.0f * wt, qn);
        qn = fmaf(bh * bh, Gtt, qn);
        q = qn;
        // scaled-w update over aligned 4-blocks; u <= t updates are harmless
        const float Pn = P * f;
        const float k  = bh * __builtin_amdgcn_rcpf(Pn);
        #pragma unroll
        for (int m4 = 0; m4 < 8; ++m4) {
            if (m4 < (t >> 2)) continue;          // blocks fully in the past
            const float4 g = *(const float4*)&Gs[t * GSTRIDE + 4 * m4];  // broadcast b128
            w[4 * m4 + 0] = fmaf(-k, g.x, w[4 * m4 + 0]);
            w[4 * m4 + 1] = fmaf(-k, g.y, w[4 * m4 + 1]);
            w[4 * m4 + 2] = fmaf(-k, g.z, w[4 * m4 + 2]);
            w[4 * m4 + 3] = fmaf(-k, g.w, w[4 * m4 + 3]);
        }
        P = Pn;
    }
    ld += __logf(prod);

    lp[(size_t)c * N + n] = -0.5f * (D_LOG_2PI + q) + ld;
}

// ---------------------------------------------------------------------------
// Kernel L: logits via MFMA. lgT[c][n] = x[n].W[:,c] + b[c].
// ---------------------------------------------------------------------------
__global__ __launch_bounds__(256) void logits_kernel(
        const unsigned short* __restrict__ xbf,
        const unsigned short* __restrict__ wtbf,
        const float* __restrict__ b,
        float* __restrict__ lgT) {
    const int wv   = threadIdx.x >> 6;
    const int ln   = threadIdx.x & 63;
    const int col  = ln & 15;
    const int quad = ln >> 4;
    const int n0   = (blockIdx.x * 4 + wv) * 16;

    const unsigned short* bp_ = xbf + (size_t)(n0 + col) * D + quad * 8;
    const short8x B0 = *(const short8x*)(bp_);
    const short8x B1 = *(const short8x*)(bp_ + 32);

    #pragma unroll
    for (int ct = 0; ct < 7; ++ct) {
        const unsigned short* apq = wtbf + (size_t)(ct * 16 + col) * D + quad * 8;
        const short8x A0 = *(const short8x*)(apq);
        const short8x A1 = *(const short8x*)(apq + 32);
        floatx4 acc = (floatx4)(0.0f);
        acc = __builtin_amdgcn_mfma_f32_16x16x32_bf16(A0, B0, acc, 0, 0, 0);
        acc = __builtin_amdgcn_mfma_f32_16x16x32_bf16(A1, B1, acc, 0, 0, 0);
        #pragma unroll
        for (int j = 0; j < 4; ++j) {
            const int cc = ct * 16 + quad * 4 + j;   // C/D: row=quad*4+j, col=n
            if (cc < C)
                lgT[(size_t)cc * N + n0 + col] = acc[j] + b[cc];
        }
    }
}

// ---------------------------------------------------------------------------
// Kernel C: epilogue (pure reduction). 512 blocks x 256 thr; 16 samples/
// block, 16 lanes/sample; lp & logit tiles staged coalesced into LDS.
// ---------------------------------------------------------------------------
__global__ __launch_bounds__(256) void epilogue_kernel(
        const float* __restrict__ lp,
        const float* __restrict__ lgT,
        const int* __restrict__ labels,
        const float* __restrict__ freq,
        float* __restrict__ out) {
    const int n0  = blockIdx.x * SB;
    const int tid = threadIdx.x;

    __shared__ float lps[SB][101];   // pad 101
    __shared__ float lgs[SB][101];
    __shared__ float lf[C];
    __shared__ int   lbl[SB];

    for (int i = tid; i < C * SB; i += 256) {          // coalesced 16-runs
        const int cc = i >> 4, s = i & (SB - 1);
        lps[s][cc] = lp[(size_t)cc * N + n0 + s];
        lgs[s][cc] = lgT[(size_t)cc * N + n0 + s];
    }
    if (tid < C) lf[tid] = __logf(freq[tid]);
    if (tid < SB) lbl[tid] = labels[n0 + tid];
    __syncthreads();

    const int s = tid >> 4;          // sample in tile (16-groups in-wave)
    const int k = tid & 15;          // lane within sample group
    const int n = n0 + s;

    float lgt[7];
    float lm = -INFINITY;
    float vm = -INFINITY, vs = 0.0f;   // online logsumexp partial (lp+lf)
    #pragma unroll
    for (int j = 0; j < 7; ++j) {
        const int cc = k + 16 * j;
        if (cc < C) {
            const float v = lps[s][cc] + lf[cc];
            const float m2 = fmaxf(vm, v);
            vs = vs * __expf(vm - m2) + __expf(v - m2);
            vm = m2;
            lgt[j] = lgs[s][cc];
            lm = fmaxf(lm, lgt[j]);
        } else lgt[j] = -INFINITY;
    }

    #pragma unroll
    for (int off = 8; off >= 1; off >>= 1) {
        const float om = __shfl_xor(vm, off, 16);
        const float os = __shfl_xor(vs, off, 16);
        const float m2 = fmaxf(vm, om);
        vs = vs * __expf(vm - m2) + os * __expf(om - m2);
        vm = m2;
        lm = fmaxf(lm, __shfl_xor(lm, off, 16));
    }
    const float marg = vm + __logf(vs);
    const float ev = __expf(fminf(marg + EV_BUDGET_F, LOG_EV_CLAMP_F));

    float ls = 0.0f;
    #pragma unroll
    for (int j = 0; j < 7; ++j)
        if (k + 16 * j < C) ls += __expf(lgt[j] - lm);
    #pragma unroll
    for (int off = 8; off >= 1; off >>= 1)
        ls += __shfl_xor(ls, off, 16);

    const float inv = ev / ls;
    float* __restrict__ outr = out + (size_t)n * (C + 1);
    #pragma unroll
    for (int j = 0; j < 7; ++j) {
        const int cc = k + 16 * j;
        if (cc < C) outr[cc] = log1pf(__expf(lgt[j] - lm) * inv);
    }
    if (k == 0) outr[C] = lps[s][lbl[s]];
}

// ---------------------------------------------------------------------------
extern "C" void kernel_launch(void* const* d_in, const int* in_sizes, int n_in,
                              void* d_out, int out_size, void* d_ws, size_t ws_size,
                              hipStream_t stream) {
    const float* x      = (const float*)d_in[0];
    const int*   labels = (const int*)  d_in[1];
    const float* freq   = (const float*)d_in[2];
    const float* z0     = (const float*)d_in[3];
    const float* ap     = (const float*)d_in[4];
    const float* bp     = (const float*)d_in[5];
    const float* W      = (const float*)d_in[6];
    const float* b      = (const float*)d_in[7];
    float* out = (float*)d_out;

    // Workspace (floats): lp[C*N] | lgT[C*N] | Gp | alpha | beta | z0bf | xbf | wtbf | q0
    float* ws     = (float*)d_ws;
    float* lp     = ws;
    float* lgT    = lp + (size_t)C * N;
    float* Gp     = lgT + (size_t)C * N;
    float* alphas = Gp + (size_t)C * T * GSTRIDE;
    float* betas  = alphas + (size_t)C * T;
    unsigned short* z0bf = (unsigned short*)(betas + (size_t)C * T);
    unsigned short* xbf  = z0bf + (size_t)C * ZROWS * D;
    unsigned short* wtbf = xbf + (size_t)N * D;
    float* q0     = (float*)(wtbf + (size_t)CROWS * D);

    megaprep_kernel<<<384, 256, 0, stream>>>(x, z0, ap, bp, W,
                                             xbf, q0, Gp, alphas, betas, z0bf, wtbf);
    flow_kernel<<<dim3(N / 256, C), 256, 0, stream>>>(xbf, q0, z0bf, Gp, alphas, betas, lp);
    logits_kernel<<<N / 64, 256, 0, stream>>>(xbf, wtbf, b, lgT);
    epilogue_kernel<<<N / SB, 256, 0, stream>>>(lp, lgT, labels, freq, out);
}

// Round 9
// 151.519 us; speedup vs baseline: 1.3362x; 1.0144x over previous
//
#include <hip/hip_runtime.h>
#include <math.h>

// Problem constants (fixed by the reference setup_inputs).
#define N 8192
#define D 64
#define C 100
#define T 30
#define GSTRIDE 32   // padded leading dim of per-class Gram rows
#define ZROWS 32     // z0 rows padded 30 -> 32 for MFMA u-tiles
#define CROWS 112    // W^T rows padded 100 -> 112 (7 MFMA c-tiles)
#define WSTRIDE 20   // per-wave transpose row stride (16 u's + 4 pad)
#define SB 16        // epilogue samples per block

static constexpr float D_LOG_2PI      = 117.62413225019811f; // D * log(2*pi)
static constexpr float EV_BUDGET_F    = 80.992775903017304f; // 0.5 * D * log(4*pi)
static constexpr float LOG_EV_CLAMP_F = 10.0f;

typedef __attribute__((ext_vector_type(8))) short short8x;   // 8 x bf16 bits
typedef __attribute__((ext_vector_type(4))) float floatx4;   // MFMA C/D frag

static __device__ __forceinline__ unsigned short f2bf(float f) {
    __bf16 h = (__bf16)f;                       // RNE convert
    return __builtin_bit_cast(unsigned short, h);
}

// ---------------------------------------------------------------------------
// Kernel MP: merged prep (one launch).
//   blocks [0,256):   xprep  — x -> bf16, q0[n] = ||x_n||^2
//   blocks [256,356): class prep — Gram, softplus params, bf16 z0
//   blocks [356,384): wprep  — pack W^T bf16 padded to 112 rows
// ---------------------------------------------------------------------------
__global__ __launch_bounds__(256) void megaprep_kernel(
        const float* __restrict__ x,
        const float* __restrict__ z0,
        const float* __restrict__ ap,
        const float* __restrict__ bp,
        const float* __restrict__ W,
        unsigned short* __restrict__ xbf,
        float* __restrict__ q0,
        float* __restrict__ Gp,
        float* __restrict__ alphas,
        float* __restrict__ betas,
        unsigned short* __restrict__ z0bf,
        unsigned short* __restrict__ wtbf) {
    const int blk = blockIdx.x;

    if (blk < 256) {                         // ---- xprep ----
        const int r = blk * 32 + (threadIdx.x >> 3);
        const int e = threadIdx.x & 7;
        const float4* xp = (const float4*)(x + (size_t)r * D + e * 8);
        const float4 a = xp[0], b = xp[1];
        short8x o;
        o[0] = f2bf(a.x); o[1] = f2bf(a.y); o[2] = f2bf(a.z); o[3] = f2bf(a.w);
        o[4] = f2bf(b.x); o[5] = f2bf(b.y); o[6] = f2bf(b.z); o[7] = f2bf(b.w);
        *(short8x*)(xbf + (size_t)r * D + e * 8) = o;
        float q = a.x*a.x + a.y*a.y + a.z*a.z + a.w*a.w
                + b.x*b.x + b.y*b.y + b.z*b.z + b.w*b.w;
        q += __shfl_xor(q, 4, 8);
        q += __shfl_xor(q, 2, 8);
        q += __shfl_xor(q, 1, 8);
        if (e == 0) q0[r] = q;
        return;
    }

    if (blk >= 356) {                        // ---- wprep ----
        const int i = (blk - 356) * 256 + threadIdx.x;   // covers CROWS*D
        const int c = i >> 6, d = i & 63;
        wtbf[i] = f2bf(c < C ? W[d * C + c] : 0.0f);
        return;
    }

    // ---- class prep ----
    const int c = blk - 256;
    __shared__ float z0s[T * D];
    for (int i = threadIdx.x; i < T * D; i += blockDim.x)
        z0s[i] = z0[c * T * D + i];
    __syncthreads();

    for (int idx = threadIdx.x; idx < T * T; idx += blockDim.x) {
        const int u = idx / T, v = idx % T;
        float s = 0.0f;
        #pragma unroll
        for (int d = 0; d < D; ++d)
            s = fmaf(z0s[u * D + d], z0s[v * D + d], s);
        Gp[(size_t)c * T * GSTRIDE + u * GSTRIDE + v] = s;
    }

    for (int i = threadIdx.x; i < ZROWS * D; i += blockDim.x) {
        const int u = i >> 6;
        z0bf[(size_t)c * ZROWS * D + i] = f2bf(u < T ? z0s[u * D + (i & 63)] : 0.0f);
    }

    if (threadIdx.x < T) {
        const float a = ap[c * T + threadIdx.x];
        const float b = bp[c * T + threadIdx.x];
        const float spa = fmaxf(a, 0.0f) + log1pf(expf(-fabsf(a)));
        const float spb = fmaxf(b, 0.0f) + log1pf(expf(-fabsf(b)));
        alphas[c * T + threadIdx.x] = spa;
        betas[c * T + threadIdx.x]  = -spa + spb;
    }
}

// ---------------------------------------------------------------------------
// Kernel A: flow. Phase 1 = MFMA (mu-split); Phase 2 = Gram-trick recurrence,
// G/alpha/beta broadcast from LDS.
// REGISTER-BUDGET HISTORY (do not regress):
//   (256,6) R4: budget 85  -> 521 MB scratch spill, catastrophic.
//   (256,4) R5/R6: budget 128 -> 72 dwords/thread spilled (WRITE 230 MB).
//   (256,3) R7: budget 170 -> 13 dwords/thread still spilled (WRITE 45 MB),
//     achieved occupancy only 8.3 waves/CU (the 3rd wave never materialized).
//   (256,2) now: budget 256 -> zero spill; achieved occupancy unchanged
//     (measured 26% == 2 waves/EU already).
// ---------------------------------------------------------------------------
__global__ __launch_bounds__(256, 2) void flow_kernel(
        const unsigned short* __restrict__ xbf,
        const float* __restrict__ q0g,
        const unsigned short* __restrict__ z0bf,
        const float* __restrict__ Gp,
        const float* __restrict__ alphas,
        const float* __restrict__ betas,
        float* __restrict__ lp) {
    const int c    = blockIdx.y;
    const int wv   = threadIdx.x >> 6;
    const int ln   = threadIdx.x & 63;
    const int col  = ln & 15;
    const int quad = ln >> 4;
    const int nb   = blockIdx.x * 256 + wv * 64;
    const int n    = nb + ln;

    __shared__ float Gs[T * GSTRIDE];        // 3840 B
    __shared__ float ab[64];                 // alpha[0..29] | beta at +32
    __shared__ float wlds[4][64 * WSTRIDE];  // 20480 B

    for (int i = threadIdx.x; i < T * GSTRIDE; i += 256)
        Gs[i] = Gp[(size_t)c * T * GSTRIDE + i];
    if (threadIdx.x < T) ab[threadIdx.x] = alphas[c * T + threadIdx.x];
    else if (threadIdx.x >= 32 && threadIdx.x < 32 + T)
        ab[threadIdx.x] = betas[c * T + (threadIdx.x - 32)];
    __syncthreads();

    const unsigned short* zb = z0bf + (size_t)c * ZROWS * D;
    float w[ZROWS];

    #pragma unroll
    for (int mu = 0; mu < 2; ++mu) {
        const short8x A0 = *(const short8x*)(zb + (mu * 16 + col) * D + quad * 8);
        const short8x A1 = *(const short8x*)(zb + (mu * 16 + col) * D + 32 + quad * 8);
        floatx4 acc[4];
        #pragma unroll
        for (int nt = 0; nt < 4; ++nt) acc[nt] = (floatx4)(0.0f);
        #pragma unroll
        for (int nt = 0; nt < 4; ++nt) {
            const unsigned short* bp_ = xbf + (size_t)(nb + nt * 16 + col) * D + quad * 8;
            const short8x B0 = *(const short8x*)(bp_);
            acc[nt] = __builtin_amdgcn_mfma_f32_16x16x32_bf16(A0, B0, acc[nt], 0, 0, 0);
            const short8x B1 = *(const short8x*)(bp_ + 32);
            acc[nt] = __builtin_amdgcn_mfma_f32_16x16x32_bf16(A1, B1, acc[nt], 0, 0, 0);
        }
        // per-wave transpose through LDS (same-wave lockstep, no barrier)
        #pragma unroll
        for (int nt = 0; nt < 4; ++nt)
            *(floatx4*)&wlds[wv][(nt * 16 + col) * WSTRIDE + quad * 4] = acc[nt];
        #pragma unroll
        for (int j = 0; j < 4; ++j) {
            const float4 t = *(const float4*)&wlds[wv][ln * WSTRIDE + j * 4];
            w[mu * 16 + 4 * j + 0] = t.x; w[mu * 16 + 4 * j + 1] = t.y;
            w[mu * 16 + 4 * j + 2] = t.z; w[mu * 16 + 4 * j + 3] = t.w;
        }
    }

    // ---- Phase 2 (verified): true w_t[u] = P*w[u]; q = ||z_t||^2 ----
    float q    = q0g[n];
    float P    = 1.0f;
    float prod = 1.0f;
    float ld   = 0.0f;
    #pragma unroll
    for (int t = 0; t < T; ++t) {
        const float Gtt   = Gs[t * GSTRIDE + t];   // broadcast ds_read
        const float alpha = ab[t];
        const float beta  = ab[32 + t];
        const float wt    = P * w[t];
        float r2 = fmaf(-2.0f, wt, q) + Gtt;
        r2 = fmaxf(r2, 0.0f);
        const float r  = __builtin_amdgcn_sqrtf(r2);
        const float h  = __builtin_amdgcn_rcpf(alpha + r);
        const float bh = beta * h;
        const float f  = 1.0f + bh;
        // det factor: f^63 * (1 + bh*alpha*h);  (1 - h*r == alpha*h)
        const float f2 = f * f, f4 = f2 * f2, f8 = f4 * f4;
        const float f16 = f8 * f8, f32v = f16 * f16;
        float p = f32v * f16; p *= f8; p *= f4; p *= f2; p *= f;  // f^63
        p *= fmaf(bh * alpha, h, 1.0f);
        prod *= p;
        if ((t % 6) == 5) { ld += __logf(prod); prod = 1.0f; }
        // q_{t+1} = f^2 q - 2 f bh wt + bh^2 Gtt
        const float m = bh * f;
        float qn = f2 * q;
        qn = fmaf(m, -2.0f * wt, qn);
        qn = fmaf(bh * bh, Gtt, qn);
        q = qn;
        // scaled-w update over aligned 4-blocks; u <= t updates are harmless
        const float Pn = P * f;
        const float k  = bh * __builtin_amdgcn_rcpf(Pn);
        #pragma unroll
        for (int m4 = 0; m4 < 8; ++m4) {
            if (m4 < (t >> 2)) continue;          // blocks fully in the past
            const float4 g = *(const float4*)&Gs[t * GSTRIDE + 4 * m4];  // broadcast b128
            w[4 * m4 + 0] = fmaf(-k, g.x, w[4 * m4 + 0]);
            w[4 * m4 + 1] = fmaf(-k, g.y, w[4 * m4 + 1]);
            w[4 * m4 + 2] = fmaf(-k, g.z, w[4 * m4 + 2]);
            w[4 * m4 + 3] = fmaf(-k, g.w, w[4 * m4 + 3]);
        }
        P = Pn;
    }
    ld += __logf(prod);

    lp[(size_t)c * N + n] = -0.5f * (D_LOG_2PI + q) + ld;
}

// ---------------------------------------------------------------------------
// Kernel C: epilogue with MFMA-fused logits. 512 blocks x 256 thr.
// Wave 0 computes the 16 samples' logits (7 MFMA c-tiles) into LDS while
// waves 1-3 stage the lp tile coalesced + lf/bsm/lbl (FIXED coverage: R8's
// first cut left lf[64..99] uninitialized and never wrote lbl).
// ---------------------------------------------------------------------------
__global__ __launch_bounds__(256) void epilogue_kernel(
        const float* __restrict__ lp,
        const unsigned short* __restrict__ xbf,
        const unsigned short* __restrict__ wtbf,
        const float* __restrict__ b,
        const int* __restrict__ labels,
        const float* __restrict__ freq,
        float* __restrict__ out) {
    const int n0  = blockIdx.x * SB;
    const int tid = threadIdx.x;
    const int wv  = tid >> 6;
    const int ln  = tid & 63;

    __shared__ float lps[SB][101];   // pad 101
    __shared__ float lgs[SB][CROWS]; // raw logits (bias added later)
    __shared__ float lf[C];
    __shared__ float bsm[C];
    __shared__ int   lbl[SB];

    if (wv == 0) {
        // ---- logits via MFMA: A = W^T tile (m=c), B = x (col=n) ----
        const int col  = ln & 15;
        const int quad = ln >> 4;
        const unsigned short* bp_ = xbf + (size_t)(n0 + col) * D + quad * 8;
        const short8x B0 = *(const short8x*)(bp_);
        const short8x B1 = *(const short8x*)(bp_ + 32);
        #pragma unroll
        for (int ct = 0; ct < 7; ++ct) {
            const unsigned short* apq = wtbf + (size_t)(ct * 16 + col) * D + quad * 8;
            const short8x A0 = *(const short8x*)(apq);
            const short8x A1 = *(const short8x*)(apq + 32);
            floatx4 acc = (floatx4)(0.0f);
            acc = __builtin_amdgcn_mfma_f32_16x16x32_bf16(A0, B0, acc, 0, 0, 0);
            acc = __builtin_amdgcn_mfma_f32_16x16x32_bf16(A1, B1, acc, 0, 0, 0);
            #pragma unroll
            for (int j = 0; j < 4; ++j)       // C/D: row=quad*4+j (class), col=n
                lgs[col][ct * 16 + quad * 4 + j] = acc[j];
        }
    } else {
        // ---- waves 1-3: stage lp tile (1600 floats), coalesced 16-runs ----
        for (int i = tid - 64; i < C * SB; i += 192) {
            const int cc = i >> 4, s = i & (SB - 1);
            lps[s][cc] = lp[(size_t)cc * N + n0 + s];
        }
        // lf/bsm: threads 64..163 cover all C=100 entries
        if (tid - 64 < C) {
            const int t2 = tid - 64;
            lf[t2]  = __logf(freq[t2]);
            bsm[t2] = b[t2];
        }
        // lbl: threads 192..207 cover SB=16 entries
        if (tid >= 192 && tid < 192 + SB)
            lbl[tid - 192] = labels[n0 + (tid - 192)];
    }
    __syncthreads();

    const int s = tid >> 4;          // sample in tile (16-groups in-wave)
    const int k = tid & 15;          // lane within sample group
    const int n = n0 + s;

    float lgt[7];
    float lm = -INFINITY;
    float vm = -INFINITY, vs = 0.0f;   // online logsumexp partial (lp+lf)
    #pragma unroll
    for (int j = 0; j < 7; ++j) {
        const int cc = k + 16 * j;
        if (cc < C) {
            const float v = lps[s][cc] + lf[cc];
            const float m2 = fmaxf(vm, v);
            vs = vs * __expf(vm - m2) + __expf(v - m2);
            vm = m2;
            lgt[j] = lgs[s][cc] + bsm[cc];
            lm = fmaxf(lm, lgt[j]);
        } else lgt[j] = -INFINITY;
    }

    #pragma unroll
    for (int off = 8; off >= 1; off >>= 1) {
        const float om = __shfl_xor(vm, off, 16);
        const float os = __shfl_xor(vs, off, 16);
        const float m2 = fmaxf(vm, om);
        vs = vs * __expf(vm - m2) + os * __expf(om - m2);
        vm = m2;
        lm = fmaxf(lm, __shfl_xor(lm, off, 16));
    }
    const float marg = vm + __logf(vs);
    const float ev = __expf(fminf(marg + EV_BUDGET_F, LOG_EV_CLAMP_F));

    float ls = 0.0f;
    #pragma unroll
    for (int j = 0; j < 7; ++j)
        if (k + 16 * j < C) ls += __expf(lgt[j] - lm);
    #pragma unroll
    for (int off = 8; off >= 1; off >>= 1)
        ls += __shfl_xor(ls, off, 16);

    const float inv = ev / ls;
    float* __restrict__ outr = out + (size_t)n * (C + 1);
    #pragma unroll
    for (int j = 0; j < 7; ++j) {
        const int cc = k + 16 * j;
        if (cc < C) outr[cc] = log1pf(__expf(lgt[j] - lm) * inv);
    }
    if (k == 0) outr[C] = lps[s][lbl[s]];
}

// ---------------------------------------------------------------------------
extern "C" void kernel_launch(void* const* d_in, const int* in_sizes, int n_in,
                              void* d_out, int out_size, void* d_ws, size_t ws_size,
                              hipStream_t stream) {
    const float* x      = (const float*)d_in[0];
    const int*   labels = (const int*)  d_in[1];
    const float* freq   = (const float*)d_in[2];
    const float* z0     = (const float*)d_in[3];
    const float* ap     = (const float*)d_in[4];
    const float* bp     = (const float*)d_in[5];
    const float* W      = (const float*)d_in[6];
    const float* b      = (const float*)d_in[7];
    float* out = (float*)d_out;

    // Workspace (floats): lp[C*N] | Gp | alpha | beta | z0bf | xbf | wtbf | q0
    float* ws     = (float*)d_ws;
    float* lp     = ws;
    float* Gp     = lp + (size_t)C * N;
    float* alphas = Gp + (size_t)C * T * GSTRIDE;
    float* betas  = alphas + (size_t)C * T;
    unsigned short* z0bf = (unsigned short*)(betas + (size_t)C * T);
    unsigned short* xbf  = z0bf + (size_t)C * ZROWS * D;
    unsigned short* wtbf = xbf + (size_t)N * D;
    float* q0     = (float*)(wtbf + (size_t)CROWS * D);

    megaprep_kernel<<<384, 256, 0, stream>>>(x, z0, ap, bp, W,
                                             xbf, q0, Gp, alphas, betas, z0bf, wtbf);
    flow_kernel<<<dim3(N / 256, C), 256, 0, stream>>>(xbf, q0, z0bf, Gp, alphas, betas, lp);
    epilogue_kernel<<<N / SB, 256, 0, stream>>>(lp, xbf, wtbf, b, labels, freq, out);
}

// Round 10
// 127.317 us; speedup vs baseline: 1.5902x; 1.1901x over previous
//
#include <hip/hip_runtime.h>
#include <math.h>

// Problem constants (fixed by the reference setup_inputs).
#define N 8192
#define D 64
#define C 100
#define T 30
#define GSTRIDE 32   // padded leading dim of per-class Gram rows
#define ZROWS 32     // z0 rows padded 30 -> 32 for MFMA u-tiles
#define CROWS 112    // W^T rows padded 100 -> 112 (7 MFMA c-tiles)
#define WSTRIDE 20   // per-wave transpose row stride (16 u's + 4 pad)
#define SB 16        // epilogue samples per block

static constexpr float D_LOG_2PI      = 117.62413225019811f; // D * log(2*pi)
static constexpr float EV_BUDGET_F    = 80.992775903017304f; // 0.5 * D * log(4*pi)
static constexpr float LOG_EV_CLAMP_F = 10.0f;

typedef __attribute__((ext_vector_type(8))) short short8x;   // 8 x bf16 bits
typedef __attribute__((ext_vector_type(4))) float floatx4;   // MFMA C/D frag

static __device__ __forceinline__ unsigned short f2bf(float f) {
    __bf16 h = (__bf16)f;                       // RNE convert
    return __builtin_bit_cast(unsigned short, h);
}

// ---------------------------------------------------------------------------
// Kernel MP: merged prep (one launch). Unchanged from R9 (verified).
// ---------------------------------------------------------------------------
__global__ __launch_bounds__(256) void megaprep_kernel(
        const float* __restrict__ x,
        const float* __restrict__ z0,
        const float* __restrict__ ap,
        const float* __restrict__ bp,
        const float* __restrict__ W,
        unsigned short* __restrict__ xbf,
        float* __restrict__ q0,
        float* __restrict__ Gp,
        float* __restrict__ alphas,
        float* __restrict__ betas,
        unsigned short* __restrict__ z0bf,
        unsigned short* __restrict__ wtbf) {
    const int blk = blockIdx.x;

    if (blk < 256) {                         // ---- xprep ----
        const int r = blk * 32 + (threadIdx.x >> 3);
        const int e = threadIdx.x & 7;
        const float4* xp = (const float4*)(x + (size_t)r * D + e * 8);
        const float4 a = xp[0], b = xp[1];
        short8x o;
        o[0] = f2bf(a.x); o[1] = f2bf(a.y); o[2] = f2bf(a.z); o[3] = f2bf(a.w);
        o[4] = f2bf(b.x); o[5] = f2bf(b.y); o[6] = f2bf(b.z); o[7] = f2bf(b.w);
        *(short8x*)(xbf + (size_t)r * D + e * 8) = o;
        float q = a.x*a.x + a.y*a.y + a.z*a.z + a.w*a.w
                + b.x*b.x + b.y*b.y + b.z*b.z + b.w*b.w;
        q += __shfl_xor(q, 4, 8);
        q += __shfl_xor(q, 2, 8);
        q += __shfl_xor(q, 1, 8);
        if (e == 0) q0[r] = q;
        return;
    }

    if (blk >= 356) {                        // ---- wprep ----
        const int i = (blk - 356) * 256 + threadIdx.x;   // covers CROWS*D
        const int c = i >> 6, d = i & 63;
        wtbf[i] = f2bf(c < C ? W[d * C + c] : 0.0f);
        return;
    }

    // ---- class prep ----
    const int c = blk - 256;
    __shared__ float z0s[T * D];
    for (int i = threadIdx.x; i < T * D; i += blockDim.x)
        z0s[i] = z0[c * T * D + i];
    __syncthreads();

    for (int idx = threadIdx.x; idx < T * T; idx += blockDim.x) {
        const int u = idx / T, v = idx % T;
        float s = 0.0f;
        #pragma unroll
        for (int d = 0; d < D; ++d)
            s = fmaf(z0s[u * D + d], z0s[v * D + d], s);
        Gp[(size_t)c * T * GSTRIDE + u * GSTRIDE + v] = s;
    }

    for (int i = threadIdx.x; i < ZROWS * D; i += blockDim.x) {
        const int u = i >> 6;
        z0bf[(size_t)c * ZROWS * D + i] = f2bf(u < T ? z0s[u * D + (i & 63)] : 0.0f);
    }

    if (threadIdx.x < T) {
        const float a = ap[c * T + threadIdx.x];
        const float b = bp[c * T + threadIdx.x];
        const float spa = fmaxf(a, 0.0f) + log1pf(expf(-fabsf(a)));
        const float spb = fmaxf(b, 0.0f) + log1pf(expf(-fabsf(b)));
        alphas[c * T + threadIdx.x] = spa;
        betas[c * T + threadIdx.x]  = -spa + spb;
    }
}

// ---------------------------------------------------------------------------
// Kernel A: flow, 2 SAMPLES PER THREAD (128/wave). R9 pipe analysis: the
// per-CU LDS pipe (~2100 cyc/wave of broadcast ds_read_b128 G rows, one pipe
// per CU vs 4 SIMDs) was the bottleneck at ~44 us; VALU only ~11 us. Serving
// 2 samples per G-row read halves LDS traffic per sample. Also: (alpha,beta,
// Gtt) packed into one b128 broadcast per step; log-det via two running
// products (ld = 63*log(pf) + log(pg) at the end) instead of f^63 powering.
// REGISTER-BUDGET HISTORY (do not regress):
//   (256,6) R4: spill catastrophic. (256,4) R5/R6: 72 dw/thread spilled.
//   (256,3) R7: 13 dw/thread spilled. (256,2) R9: ZERO spill at VGPR=92.
//   Now live set grows ~+70 (w[2][32] + dual scalars) -> ~160, still < 256.
//   WRITE_SIZE == 3200 KB is the no-spill sentinel; watch it.
// ---------------------------------------------------------------------------
__global__ __launch_bounds__(256, 2) void flow_kernel(
        const unsigned short* __restrict__ xbf,
        const float* __restrict__ q0g,
        const unsigned short* __restrict__ z0bf,
        const float* __restrict__ Gp,
        const float* __restrict__ alphas,
        const float* __restrict__ betas,
        float* __restrict__ lp) {
    const int c    = blockIdx.y;
    const int wv   = threadIdx.x >> 6;
    const int ln   = threadIdx.x & 63;
    const int col  = ln & 15;
    const int quad = ln >> 4;
    const int nb   = blockIdx.x * 512 + wv * 128;  // wave's 128-sample base

    __shared__ float Gs[T * GSTRIDE];        // 3840 B
    __shared__ float abg[T * 4];             // (alpha, beta, Gtt, 0) per t
    __shared__ float wlds[4][64 * WSTRIDE];  // 20480 B

    for (int i = threadIdx.x; i < T * GSTRIDE; i += 256)
        Gs[i] = Gp[(size_t)c * T * GSTRIDE + i];
    if (threadIdx.x < T) {
        const int t = threadIdx.x;
        abg[t * 4 + 0] = alphas[c * T + t];
        abg[t * 4 + 1] = betas[c * T + t];
        abg[t * 4 + 2] = Gp[(size_t)c * T * GSTRIDE + t * GSTRIDE + t];
        abg[t * 4 + 3] = 0.0f;
    }
    __syncthreads();

    // ---- Phase 1: MFMA, 2 halves x 2 mu; A frags hoisted (shared) ----
    const unsigned short* zb = z0bf + (size_t)c * ZROWS * D;
    short8x A[2][2];
    #pragma unroll
    for (int mu = 0; mu < 2; ++mu) {
        A[mu][0] = *(const short8x*)(zb + (mu * 16 + col) * D + quad * 8);
        A[mu][1] = *(const short8x*)(zb + (mu * 16 + col) * D + 32 + quad * 8);
    }

    float w[2][ZROWS];
    #pragma unroll
    for (int half = 0; half < 2; ++half) {
        const int hb = nb + half * 64;
        #pragma unroll
        for (int mu = 0; mu < 2; ++mu) {
            floatx4 acc[4];
            #pragma unroll
            for (int nt = 0; nt < 4; ++nt) acc[nt] = (floatx4)(0.0f);
            #pragma unroll
            for (int nt = 0; nt < 4; ++nt) {
                const unsigned short* bp_ =
                    xbf + (size_t)(hb + nt * 16 + col) * D + quad * 8;
                const short8x B0 = *(const short8x*)(bp_);
                acc[nt] = __builtin_amdgcn_mfma_f32_16x16x32_bf16(A[mu][0], B0, acc[nt], 0, 0, 0);
                const short8x B1 = *(const short8x*)(bp_ + 32);
                acc[nt] = __builtin_amdgcn_mfma_f32_16x16x32_bf16(A[mu][1], B1, acc[nt], 0, 0, 0);
            }
            // per-wave transpose through LDS (same-wave lockstep, no barrier)
            #pragma unroll
            for (int nt = 0; nt < 4; ++nt)
                *(floatx4*)&wlds[wv][(nt * 16 + col) * WSTRIDE + quad * 4] = acc[nt];
            #pragma unroll
            for (int j = 0; j < 4; ++j) {
                const float4 t = *(const float4*)&wlds[wv][ln * WSTRIDE + j * 4];
                w[half][mu * 16 + 4 * j + 0] = t.x;
                w[half][mu * 16 + 4 * j + 1] = t.y;
                w[half][mu * 16 + 4 * j + 2] = t.z;
                w[half][mu * 16 + 4 * j + 3] = t.w;
            }
        }
    }

    // ---- Phase 2: dual-sample Gram-trick recurrence ----
    float qA = q0g[nb + ln], qB = q0g[nb + 64 + ln];
    float PA = 1.0f, PB = 1.0f;
    float pfA = 1.0f, pfB = 1.0f;   // prod of f
    float pgA = 1.0f, pgB = 1.0f;   // prod of (1 + bh*alpha*h)
    #pragma unroll
    for (int t = 0; t < T; ++t) {
        const floatx4 av = *(const floatx4*)&abg[t * 4];   // one b128 broadcast
        const float alpha = av[0], beta = av[1], Gtt = av[2];

        // sample A scalar chain
        const float wtA = PA * w[0][t];
        float r2A = fmaf(-2.0f, wtA, qA) + Gtt;
        r2A = fmaxf(r2A, 0.0f);
        const float rA  = __builtin_amdgcn_sqrtf(r2A);
        const float hA  = __builtin_amdgcn_rcpf(alpha + rA);
        const float bhA = beta * hA;
        const float fA  = 1.0f + bhA;
        pfA *= fA;
        pgA *= fmaf(bhA * alpha, hA, 1.0f);
        float qnA = fA * fA * qA;
        qnA = fmaf(bhA * fA, -2.0f * wtA, qnA);
        qnA = fmaf(bhA * bhA, Gtt, qnA);
        qA = qnA;
        const float PnA = PA * fA;
        const float kA  = bhA * __builtin_amdgcn_rcpf(PnA);
        PA = PnA;

        // sample B scalar chain (independent -> ILP with A)
        const float wtB = PB * w[1][t];
        float r2B = fmaf(-2.0f, wtB, qB) + Gtt;
        r2B = fmaxf(r2B, 0.0f);
        const float rB  = __builtin_amdgcn_sqrtf(r2B);
        const float hB  = __builtin_amdgcn_rcpf(alpha + rB);
        const float bhB = beta * hB;
        const float fB  = 1.0f + bhB;
        pfB *= fB;
        pgB *= fmaf(bhB * alpha, hB, 1.0f);
        float qnB = fB * fB * qB;
        qnB = fmaf(bhB * fB, -2.0f * wtB, qnB);
        qnB = fmaf(bhB * bhB, Gtt, qnB);
        qB = qnB;
        const float PnB = PB * fB;
        const float kB  = bhB * __builtin_amdgcn_rcpf(PnB);
        PB = PnB;

        // joint w-update: one G-row b128 read feeds BOTH samples (8 FMA)
        #pragma unroll
        for (int m4 = 0; m4 < 8; ++m4) {
            if (m4 < (t >> 2)) continue;          // blocks fully in the past
            const float4 g = *(const float4*)&Gs[t * GSTRIDE + 4 * m4];
            w[0][4 * m4 + 0] = fmaf(-kA, g.x, w[0][4 * m4 + 0]);
            w[0][4 * m4 + 1] = fmaf(-kA, g.y, w[0][4 * m4 + 1]);
            w[0][4 * m4 + 2] = fmaf(-kA, g.z, w[0][4 * m4 + 2]);
            w[0][4 * m4 + 3] = fmaf(-kA, g.w, w[0][4 * m4 + 3]);
            w[1][4 * m4 + 0] = fmaf(-kB, g.x, w[1][4 * m4 + 0]);
            w[1][4 * m4 + 1] = fmaf(-kB, g.y, w[1][4 * m4 + 1]);
            w[1][4 * m4 + 2] = fmaf(-kB, g.z, w[1][4 * m4 + 2]);
            w[1][4 * m4 + 3] = fmaf(-kB, g.w, w[1][4 * m4 + 3]);
        }
    }
    const float ldA = 63.0f * __logf(pfA) + __logf(pgA);
    const float ldB = 63.0f * __logf(pfB) + __logf(pgB);

    lp[(size_t)c * N + nb + ln]      = -0.5f * (D_LOG_2PI + qA) + ldA;
    lp[(size_t)c * N + nb + 64 + ln] = -0.5f * (D_LOG_2PI + qB) + ldB;
}

// ---------------------------------------------------------------------------
// Kernel C: epilogue with MFMA-fused logits. Unchanged from R9 (verified).
// ---------------------------------------------------------------------------
__global__ __launch_bounds__(256) void epilogue_kernel(
        const float* __restrict__ lp,
        const unsigned short* __restrict__ xbf,
        const unsigned short* __restrict__ wtbf,
        const float* __restrict__ b,
        const int* __restrict__ labels,
        const float* __restrict__ freq,
        float* __restrict__ out) {
    const int n0  = blockIdx.x * SB;
    const int tid = threadIdx.x;
    const int wv  = tid >> 6;
    const int ln  = tid & 63;

    __shared__ float lps[SB][101];   // pad 101
    __shared__ float lgs[SB][CROWS]; // raw logits (bias added later)
    __shared__ float lf[C];
    __shared__ float bsm[C];
    __shared__ int   lbl[SB];

    if (wv == 0) {
        // ---- logits via MFMA: A = W^T tile (m=c), B = x (col=n) ----
        const int col  = ln & 15;
        const int quad = ln >> 4;
        const unsigned short* bp_ = xbf + (size_t)(n0 + col) * D + quad * 8;
        const short8x B0 = *(const short8x*)(bp_);
        const short8x B1 = *(const short8x*)(bp_ + 32);
        #pragma unroll
        for (int ct = 0; ct < 7; ++ct) {
            const unsigned short* apq = wtbf + (size_t)(ct * 16 + col) * D + quad * 8;
            const short8x A0 = *(const short8x*)(apq);
            const short8x A1 = *(const short8x*)(apq + 32);
            floatx4 acc = (floatx4)(0.0f);
            acc = __builtin_amdgcn_mfma_f32_16x16x32_bf16(A0, B0, acc, 0, 0, 0);
            acc = __builtin_amdgcn_mfma_f32_16x16x32_bf16(A1, B1, acc, 0, 0, 0);
            #pragma unroll
            for (int j = 0; j < 4; ++j)       // C/D: row=quad*4+j (class), col=n
                lgs[col][ct * 16 + quad * 4 + j] = acc[j];
        }
    } else {
        // ---- waves 1-3: stage lp tile (1600 floats), coalesced 16-runs ----
        for (int i = tid - 64; i < C * SB; i += 192) {
            const int cc = i >> 4, s = i & (SB - 1);
            lps[s][cc] = lp[(size_t)cc * N + n0 + s];
        }
        // lf/bsm: threads 64..163 cover all C=100 entries
        if (tid - 64 < C) {
            const int t2 = tid - 64;
            lf[t2]  = __logf(freq[t2]);
            bsm[t2] = b[t2];
        }
        // lbl: threads 192..207 cover SB=16 entries
        if (tid >= 192 && tid < 192 + SB)
            lbl[tid - 192] = labels[n0 + (tid - 192)];
    }
    __syncthreads();

    const int s = tid >> 4;          // sample in tile (16-groups in-wave)
    const int k = tid & 15;          // lane within sample group
    const int n = n0 + s;

    float lgt[7];
    float lm = -INFINITY;
    float vm = -INFINITY, vs = 0.0f;   // online logsumexp partial (lp+lf)
    #pragma unroll
    for (int j = 0; j < 7; ++j) {
        const int cc = k + 16 * j;
        if (cc < C) {
            const float v = lps[s][cc] + lf[cc];
            const float m2 = fmaxf(vm, v);
            vs = vs * __expf(vm - m2) + __expf(v - m2);
            vm = m2;
            lgt[j] = lgs[s][cc] + bsm[cc];
            lm = fmaxf(lm, lgt[j]);
        } else lgt[j] = -INFINITY;
    }

    #pragma unroll
    for (int off = 8; off >= 1; off >>= 1) {
        const float om = __shfl_xor(vm, off, 16);
        const float os = __shfl_xor(vs, off, 16);
        const float m2 = fmaxf(vm, om);
        vs = vs * __expf(vm - m2) + os * __expf(om - m2);
        vm = m2;
        lm = fmaxf(lm, __shfl_xor(lm, off, 16));
    }
    const float marg = vm + __logf(vs);
    const float ev = __expf(fminf(marg + EV_BUDGET_F, LOG_EV_CLAMP_F));

    float ls = 0.0f;
    #pragma unroll
    for (int j = 0; j < 7; ++j)
        if (k + 16 * j < C) ls += __expf(lgt[j] - lm);
    #pragma unroll
    for (int off = 8; off >= 1; off >>= 1)
        ls += __shfl_xor(ls, off, 16);

    const float inv = ev / ls;
    float* __restrict__ outr = out + (size_t)n * (C + 1);
    #pragma unroll
    for (int j = 0; j < 7; ++j) {
        const int cc = k + 16 * j;
        if (cc < C) outr[cc] = log1pf(__expf(lgt[j] - lm) * inv);
    }
    if (k == 0) outr[C] = lps[s][lbl[s]];
}

// ---------------------------------------------------------------------------
extern "C" void kernel_launch(void* const* d_in, const int* in_sizes, int n_in,
                              void* d_out, int out_size, void* d_ws, size_t ws_size,
                              hipStream_t stream) {
    const float* x      = (const float*)d_in[0];
    const int*   labels = (const int*)  d_in[1];
    const float* freq   = (const float*)d_in[2];
    const float* z0     = (const float*)d_in[3];
    const float* ap     = (const float*)d_in[4];
    const float* bp     = (const float*)d_in[5];
    const float* W      = (const float*)d_in[6];
    const float* b      = (const float*)d_in[7];
    float* out = (float*)d_out;

    // Workspace (floats): lp[C*N] | Gp | alpha | beta | z0bf | xbf | wtbf | q0
    float* ws     = (float*)d_ws;
    float* lp     = ws;
    float* Gp     = lp + (size_t)C * N;
    float* alphas = Gp + (size_t)C * T * GSTRIDE;
    float* betas  = alphas + (size_t)C * T;
    unsigned short* z0bf = (unsigned short*)(betas + (size_t)C * T);
    unsigned short* xbf  = z0bf + (size_t)C * ZROWS * D;
    unsigned short* wtbf = xbf + (size_t)N * D;
    float* q0     = (float*)(wtbf + (size_t)CROWS * D);

    megaprep_kernel<<<384, 256, 0, stream>>>(x, z0, ap, bp, W,
                                             xbf, q0, Gp, alphas, betas, z0bf, wtbf);
    flow_kernel<<<dim3(N / 512, C), 256, 0, stream>>>(xbf, q0, z0bf, Gp, alphas, betas, lp);
    epilogue_kernel<<<N / SB, 256, 0, stream>>>(lp, xbf, wtbf, b, labels, freq, out);
}